// Round 7
// baseline (342.340 us; speedup 1.0000x reference)
//
#include <hip/hip_runtime.h>
#include <hip/hip_bf16.h>
#include <cstdint>
#include <cstddef>

// ---------------------------------------------------------------------------
// AttentionLayer: out = gamma * softmax((x@g) @ (input_h@f)^T) @ input_h + x
// B=4, W=64 (N=4096), C=C2=512, D=64.  I/O tensors are FLOAT32.
// Q,K,V,weights bf16 for MFMA; softmax + O-accum fp32.
// Fixed-max softmax: p = exp(min(s,80)-20).
// ALL MFMAs 16x16x32_bf16 (HW-verified maps):
//   A: [m=lane&15][k=(lane>>4)*8+j]   B: [n=lane&15][k=(lane>>4)*8+j]
//   C/D: col=lane&15, row=(lane>>4)*4+reg
//
// R11 (post-mortem R10): launch_bounds(1024,4) was interpreted as 4 BLOCKS/CU
// (64 waves/CU, impossible) -> allocator clamped to 8 waves/SIMD budget = 64
// VGPR -> acc[4][4] still spilled (VGPR_Count 64, WRITE 137MB).  Fix: direct
// __attribute__((amdgpu_waves_per_eu(4,4))) -> exactly 4 waves/EU -> 128-VGPR
// cap; B-wave peak live ~118 < 128, no spill.  Logic identical to R9/R10:
// waves 0-7 (A) produce P(i+1) (QK^T+exp) + stage K; waves 8-15 (B) consume
// P(i) (V loads + P@V, 64-chan slice).  Single raw barrier per window.
// Parities: A writes Pbuf[(i+1)&1], B reads Pbuf[i&1]; A reads Klds[(i+1)&1],
// stages K(i+2)->Klds[i&1] -- disjoint.
//
// ws layout (20.1MB, non-overlapping): fT 64K @0 | gT 64K @64K | Qg 2M @128K |
// Kf 2M @2.125M | Vt 16M @4.125M.
// ---------------------------------------------------------------------------

#define NPOS 4096
#define CCH  512
#define DQK  64
#define LSTR 72   // LDS row stride (elements): 144B rows, 16B-aligned frags

typedef __attribute__((ext_vector_type(8)))  short s8v;   // 8 bf16 (4 VGPR)
typedef __attribute__((ext_vector_type(4)))  short s4v;   // 4 bf16
typedef __attribute__((ext_vector_type(4)))  float f4v;

__device__ __forceinline__ float bf2f(unsigned short u) {
    unsigned int x = ((unsigned int)u) << 16;
    return __builtin_bit_cast(float, x);
}
__device__ __forceinline__ unsigned short f2bf(float f) {
    unsigned int u = __builtin_bit_cast(unsigned int, f);
    u += 0x7fffu + ((u >> 16) & 1u);   // round-to-nearest-even
    return (unsigned short)(u >> 16);
}

// Barrier with LDS visibility but NO vmcnt drain: global loads (register
// destinations, compiler-tracked deps) stay in flight across it.
__device__ __forceinline__ void sync_lds() {
    asm volatile("s_waitcnt lgkmcnt(0)" ::: "memory");
    __builtin_amdgcn_s_barrier();
}

// --------------------------- weight transpose ------------------------------
// f,g: [512,64] fp32 -> fT,gT: [64,512] bf16.
__global__ __launch_bounds__(256) void wt_kernel(
    const float* __restrict__ f, const float* __restrict__ g,
    unsigned short* __restrict__ fT, unsigned short* __restrict__ gT)
{
    int gid = blockIdx.x * 256 + threadIdx.x;   // grid 64 -> 16384 threads
    for (int e = 0; e < 4; ++e) {
        int i = e * 16384 + gid;                // 0..65535
        int which = i >> 15;
        int j = i & 32767;
        int d = j >> 9, k = j & 511;
        const float* s = which ? g : f;
        unsigned short* dst = which ? gT : fT;
        dst[j] = f2bf(s[k * 64 + d]);           // dst[d][k] = src[k][d]
    }
}

// ----------------------------- V transpose ---------------------------------
// input_h [b][n][c] fp32 -> Vt [b][c][n] bf16.  64x64 tiles through LDS
// (stride 65 breaks bank conflicts on the column gathers).
__global__ __launch_bounds__(256) void vt_kernel(
    const float* __restrict__ ih, unsigned short* __restrict__ Vt)
{
    __shared__ unsigned short T[64 * 65];
    const int tid = threadIdx.x;
    const int bidx = blockIdx.x;
    const int bb = bidx >> 9;      // batch
    const int rem = bidx & 511;
    const int ct = rem >> 6;       // c tile 0..7
    const int nt = rem & 63;       // n tile 0..63

    for (int p = 0; p < 4; ++p) {
        int idx = p * 256 + tid;           // 0..1023
        int r = idx >> 4, gg = idx & 15;   // row 0..63, float4 group 0..15
        f4v v = *(const f4v*)(ih + ((size_t)bb * NPOS + nt * 64 + r) * CCH + ct * 64 + gg * 4);
        for (int j = 0; j < 4; ++j) T[r * 65 + gg * 4 + j] = f2bf(v[j]);
    }
    __syncthreads();
    for (int p = 0; p < 2; ++p) {
        int idx = p * 256 + tid;
        int c = idx >> 3, ng = idx & 7;
        unsigned short tmp[8];
        for (int j = 0; j < 8; ++j) tmp[j] = T[(ng * 8 + j) * 65 + c];
        *(s8v*)(Vt + ((size_t)bb * CCH + ct * 64 + c) * NPOS + nt * 64 + ng * 8) = *(const s8v*)tmp;
    }
}

// ------------------------------ projections --------------------------------
// which=0: Q = x @ g   (16384 rows, K=512, 64 cols).  which=1: K = ih @ f.
// R8: reg-staged tile prefetch + sync_lds (no vmcnt drain at barriers).
__global__ __launch_bounds__(256) void proj_kernel(
    const float* __restrict__ x,  const float* __restrict__ ih,
    const unsigned short* __restrict__ gT, const unsigned short* __restrict__ fT,
    unsigned short* __restrict__ Qg, unsigned short* __restrict__ Kf)
{
    __shared__ __align__(16) short Alds[128 * LSTR];
    __shared__ __align__(16) short Wlds[64 * LSTR];
    const int tid = threadIdx.x;
    const int wave = tid >> 6, lane = tid & 63;
    const int n15 = lane & 15, quad = lane >> 4;
    const int which = blockIdx.x >> 7;
    const int rb = (blockIdx.x & 127) * 128;
    const float* src = which ? ih : x;
    const unsigned short* wT  = which ? fT : gT;
    unsigned short* dst = which ? Kf : Qg;

    f4v acc[2][4];   // [row-tile][col-tile]
    for (int i = 0; i < 2; ++i)
        for (int j = 0; j < 4; ++j)
            acc[i][j] = f4v{0.f, 0.f, 0.f, 0.f};

    f4v areg[8];
    s8v wreg[2];
    // prologue: load kc=0 tiles into registers
    for (int p = 0; p < 8; ++p) {
        int idx = p * 256 + tid;
        int r = idx >> 4, gg = idx & 15;
        areg[p] = *(const f4v*)(src + (size_t)(rb + r) * CCH + gg * 4);
    }
    for (int p = 0; p < 2; ++p) {
        int idx = p * 256 + tid;
        int c = idx >> 3, gg = idx & 7;
        wreg[p] = *(const s8v*)(wT + (size_t)c * CCH + gg * 8);
    }

    for (int kc = 0; kc < 8; ++kc) {
        // stage current tiles from registers (fp32 -> bf16 for A)
        for (int p = 0; p < 8; ++p) {
            int idx = p * 256 + tid;
            int r = idx >> 4, gg = idx & 15;
            s4v tv;
            for (int j = 0; j < 4; ++j) tv[j] = (short)f2bf(areg[p][j]);
            *(s4v*)&Alds[r * LSTR + gg * 4] = tv;
        }
        for (int p = 0; p < 2; ++p) {
            int idx = p * 256 + tid;
            int c = idx >> 3, gg = idx & 7;
            *(s8v*)&Wlds[c * LSTR + gg * 8] = wreg[p];
        }
        // prefetch kc+1 tiles into registers (stays in flight across barriers)
        if (kc < 7) {
            for (int p = 0; p < 8; ++p) {
                int idx = p * 256 + tid;
                int r = idx >> 4, gg = idx & 15;
                areg[p] = *(const f4v*)(src + (size_t)(rb + r) * CCH + (kc + 1) * 64 + gg * 4);
            }
            for (int p = 0; p < 2; ++p) {
                int idx = p * 256 + tid;
                int c = idx >> 3, gg = idx & 7;
                wreg[p] = *(const s8v*)(wT + (size_t)c * CCH + (kc + 1) * 64 + gg * 8);
            }
        }
        sync_lds();
        for (int kk = 0; kk < 2; ++kk) {       // two K=32 chunks of the 64-tile
            s8v af0 = *(const s8v*)&Alds[(wave * 32 +      n15) * LSTR + kk * 32 + quad * 8];
            s8v af1 = *(const s8v*)&Alds[(wave * 32 + 16 + n15) * LSTR + kk * 32 + quad * 8];
            for (int ct = 0; ct < 4; ++ct) {
                s8v bf = *(const s8v*)&Wlds[(ct * 16 + n15) * LSTR + kk * 32 + quad * 8];
                acc[0][ct] = __builtin_amdgcn_mfma_f32_16x16x32_bf16(af0, bf, acc[0][ct], 0, 0, 0);
                acc[1][ct] = __builtin_amdgcn_mfma_f32_16x16x32_bf16(af1, bf, acc[1][ct], 0, 0, 0);
            }
        }
        sync_lds();
    }
    for (int rt = 0; rt < 2; ++rt)
        for (int ct = 0; ct < 4; ++ct)
            for (int r = 0; r < 4; ++r) {
                int row = wave * 32 + rt * 16 + quad * 4 + r;
                int col = ct * 16 + n15;
                dst[(size_t)(rb + row) * DQK + col] = f2bf(acc[rt][ct][r]);
            }
}

// ------------------------------ flash attention ----------------------------
// One block per (batch, 64-row query tile), 1024 threads = 16 waves.
// Role-split: waves 0-7 (A) produce P(i+1) (QK^T+exp) and stage K; waves
// 8-15 (B) consume P(i) (V loads + P@V, 64-chan slice each).  Single raw
// barrier per window; A and B overlap VALU/MFMA/L2 pipes across waves.
// amdgpu_waves_per_eu(4,4): exactly 4 waves/EU -> 128-VGPR cap, no spill.
__global__ __launch_bounds__(1024)
__attribute__((amdgpu_waves_per_eu(4, 4)))
void flash_kernel(
    const unsigned short* __restrict__ Qg,
    const unsigned short* __restrict__ Kf,
    const unsigned short* __restrict__ Vt,
    const float* __restrict__ xin,
    const float* __restrict__ gptr,
    float* __restrict__ out)
{
    __shared__ __align__(16) short Klds[2 * 64 * LSTR];  // double-buffered K
    __shared__ __align__(16) short Plds[2 * 64 * LSTR];  // double-buffered P
    __shared__ float l_part[2][64];                      // per-half row partials
    __shared__ float l_s[64];

    const int tid = threadIdx.x;
    const int wave = tid >> 6;          // 0..15
    const int lane = tid & 63;
    const int n15 = lane & 15, quad = lane >> 4;
    const int bid = blockIdx.x;
    // XCD swizzle: batch b -> XCD pair so per-XCD Vt working set = 4MB.
    const int xcd = bid & 7;
    const int b = xcd >> 1;
    const int qt = (xcd & 1) + ((bid >> 3) << 1);
    const int qbase = qt * 64;

    const float SOFT_M = 20.0f;
    const bool isA = (wave < 8);
    const int NT = NPOS / 64;   // 64 windows

    // ---- A-wave state: S-tiles (ti = w>>1, mi = (w&1)*2 + mm) ----
    const int ti = wave >> 1;
    const int mi0 = (wave & 1) * 2;
    s8v qf[2];
    f4v lsum = f4v{0.f, 0.f, 0.f, 0.f};
    const int kr = tid >> 3, kg = tid & 7;   // K staging coords (tid<512)
    const unsigned short* kbase_p = Kf + ((size_t)b * NPOS + kr) * DQK + kg * 8;
    s8v kreg;

    // ---- B-wave state: 64-chan slice, acc[4][4] ----
    const int cb = (wave - 8) * 64;
    f4v acc[4][4];
    const unsigned short* vp[4];

    if (isA) {
        const unsigned short* qp =
            Qg + ((size_t)b * NPOS + qbase + ti * 16 + n15) * DQK + quad * 8;
        qf[0] = *(const s8v*)(qp);
        qf[1] = *(const s8v*)(qp + 32);
        // stage K(0), prefetch K(1)
        kreg = *(const s8v*)(kbase_p);
        *(s8v*)&Klds[kr * LSTR + kg * 8] = kreg;
        kreg = *(const s8v*)(kbase_p + (size_t)64 * DQK);
    } else {
        for (int i = 0; i < 4; ++i)
            for (int j = 0; j < 4; ++j)
                acc[i][j] = f4v{0.f, 0.f, 0.f, 0.f};
        const unsigned short* Vb = Vt + (size_t)b * CCH * NPOS;
        for (int ct = 0; ct < 4; ++ct)
            vp[ct] = Vb + (size_t)(cb + ct * 16 + n15) * NPOS + quad * 8;
    }
    sync_lds();   // Klds[0] staged

    if (isA) {
        // produce P(0) from Klds[0]
        const short* Kb = &Klds[0];
        short* Pb = &Plds[0];
        for (int mm = 0; mm < 2; ++mm) {
            const int mi = mi0 + mm;
            f4v s4 = f4v{0.f, 0.f, 0.f, 0.f};
            s8v kf0 = *(const s8v*)&Kb[(mi * 16 + n15) * LSTR + quad * 8];
            s8v kf1 = *(const s8v*)&Kb[(mi * 16 + n15) * LSTR + 32 + quad * 8];
            s4 = __builtin_amdgcn_mfma_f32_16x16x32_bf16(qf[0], kf0, s4, 0, 0, 0);
            s4 = __builtin_amdgcn_mfma_f32_16x16x32_bf16(qf[1], kf1, s4, 0, 0, 0);
            const int col = mi * 16 + n15;
            const int row0 = ti * 16 + quad * 4;
            for (int r = 0; r < 4; ++r) {
                unsigned short pb = f2bf(__expf(fminf(s4[r], 80.0f) - SOFT_M));
                Pb[(row0 + r) * LSTR + col] = (short)pb;
                lsum[r] += bf2f(pb);
            }
        }
        // stage K(1), prefetch K(2)
        *(s8v*)&Klds[64 * LSTR + kr * LSTR + kg * 8] = kreg;
        kreg = *(const s8v*)(kbase_p + (size_t)128 * DQK);
    }
    sync_lds();   // Pbuf[0] + Klds[1] ready

    for (int i = 0; i < NT; ++i) {
        if (isA) {
            // ---- produce P(i+1); stage K(i+2); prefetch K(i+3) ----
            if (i + 1 < NT) {
                const short* Kb = &Klds[((i + 1) & 1) * 64 * LSTR];
                short* Pb = &Plds[((i + 1) & 1) * 64 * LSTR];
                for (int mm = 0; mm < 2; ++mm) {
                    const int mi = mi0 + mm;
                    f4v s4 = f4v{0.f, 0.f, 0.f, 0.f};
                    s8v kf0 = *(const s8v*)&Kb[(mi * 16 + n15) * LSTR + quad * 8];
                    s8v kf1 = *(const s8v*)&Kb[(mi * 16 + n15) * LSTR + 32 + quad * 8];
                    s4 = __builtin_amdgcn_mfma_f32_16x16x32_bf16(qf[0], kf0, s4, 0, 0, 0);
                    s4 = __builtin_amdgcn_mfma_f32_16x16x32_bf16(qf[1], kf1, s4, 0, 0, 0);
                    const int col = mi * 16 + n15;
                    const int row0 = ti * 16 + quad * 4;
                    for (int r = 0; r < 4; ++r) {
                        unsigned short pb = f2bf(__expf(fminf(s4[r], 80.0f) - SOFT_M));
                        Pb[(row0 + r) * LSTR + col] = (short)pb;
                        lsum[r] += bf2f(pb);
                    }
                }
                if (i + 2 < NT)
                    *(s8v*)&Klds[(i & 1) * 64 * LSTR + kr * LSTR + kg * 8] = kreg;
                if (i + 3 < NT)
                    kreg = *(const s8v*)(kbase_p + (size_t)(i + 3) * 64 * DQK);
            }
        } else {
            // ---- consume P(i): V loads + P@V into acc ----
            const int m0 = i * 64;
            s8v vf[4][2];
            for (int ct = 0; ct < 4; ++ct) {
                vf[ct][0] = *(const s8v*)(vp[ct] + m0);
                vf[ct][1] = *(const s8v*)(vp[ct] + m0 + 32);
            }
            const short* Pb = &Plds[(i & 1) * 64 * LSTR];
            __builtin_amdgcn_s_setprio(1);
            for (int kk = 0; kk < 2; ++kk) {
                for (int q4 = 0; q4 < 4; ++q4) {
                    // per-q4 P fragment load keeps peak live regs ~118 (<128)
                    s8v af = *(const s8v*)&Pb[(q4 * 16 + n15) * LSTR + kk * 32 + quad * 8];
                    for (int ct = 0; ct < 4; ++ct)
                        acc[q4][ct] = __builtin_amdgcn_mfma_f32_16x16x32_bf16(
                            af, vf[ct][kk], acc[q4][ct], 0, 0, 0);
                }
            }
            __builtin_amdgcn_s_setprio(0);
        }
        sync_lds();
        // parities in phase i: A wrote Pbuf[(i+1)&1], B read Pbuf[i&1];
        // A read Klds[(i+1)&1], staged K(i+2)->Klds[i&1].  All disjoint.
    }

    // ---- denominator: A-waves reduce lsum -> l_s ----
    if (isA) {
        for (int d = 1; d < 16; d <<= 1)
            for (int r = 0; r < 4; ++r)
                lsum[r] += __shfl_xor(lsum[r], d);
        if (n15 == 0)
            for (int r = 0; r < 4; ++r)
                l_part[wave & 1][ti * 16 + quad * 4 + r] = lsum[r];
    }
    __syncthreads();
    if (tid < 64) l_s[tid] = l_part[0][tid] + l_part[1][tid];
    __syncthreads();

    // ---- epilogue (B-waves): out = gamma * O / l + x ----
    if (!isA) {
        const float gamma = gptr[0];
        for (int q4 = 0; q4 < 4; ++q4) {
            for (int r = 0; r < 4; ++r) {
                const int row = q4 * 16 + quad * 4 + r;
                const float sc = gamma / l_s[row];
                const size_t base = ((size_t)b * NPOS + qbase + row) * CCH;
                for (int ct = 0; ct < 4; ++ct) {
                    const int col = cb + ct * 16 + n15;
                    out[base + col] = acc[q4][ct][r] * sc + xin[base + col];
                }
            }
        }
    }
}

// ---------------------------------------------------------------------------
extern "C" void kernel_launch(void* const* d_in, const int* in_sizes, int n_in,
                              void* d_out, int out_size, void* d_ws, size_t ws_size,
                              hipStream_t stream)
{
    const float* x     = (const float*)d_in[0];
    const float* ih    = (const float*)d_in[1];
    const float* f     = (const float*)d_in[2];
    const float* g     = (const float*)d_in[3];
    const float* gamma = (const float*)d_in[4];
    float* out = (float*)d_out;

    char* ws = (char*)d_ws;
    unsigned short* fT = (unsigned short*)(ws + 0);         // 64x512 bf16 (64KB)
    unsigned short* gT = (unsigned short*)(ws + 65536);     // 64x512 bf16 (64KB)
    unsigned short* Qg = (unsigned short*)(ws + 131072);    // 16384x64 bf16 (2MB)
    unsigned short* Kf = (unsigned short*)(ws + 2228224);   // 16384x64 bf16 (2MB)
    unsigned short* Vt = (unsigned short*)(ws + 4325376);   // 4x512x4096 bf16 (16MB)
    // total ws use: 21,102,592 bytes (~20.1MB), non-overlapping.

    wt_kernel<<<64, 256, 0, stream>>>(f, g, fT, gT);
    vt_kernel<<<2048, 256, 0, stream>>>(ih, Vt);
    proj_kernel<<<256, 256, 0, stream>>>(x, ih, gT, fT, Qg, Kf);
    flash_kernel<<<256, 1024, 0, stream>>>(Qg, Kf, Vt, x, gamma, out);
}

// Round 8
// 337.189 us; speedup vs baseline: 1.0153x; 1.0153x over previous
//
#include <hip/hip_runtime.h>
#include <hip/hip_bf16.h>
#include <cstdint>
#include <cstddef>

// ---------------------------------------------------------------------------
// AttentionLayer: out = gamma * softmax((x@g) @ (input_h@f)^T) @ input_h + x
// B=4, W=64 (N=4096), C=C2=512, D=64.  I/O tensors are FLOAT32.
// Q,K,V,weights bf16 for MFMA; softmax + O-accum fp32.
// Fixed-max softmax: p = exp(min(s,80)-20).
// ALL MFMAs 16x16x32_bf16 (HW-verified maps):
//   A: [m=lane&15][k=(lane>>4)*8+j]   B: [n=lane&15][k=(lane>>4)*8+j]
//   C/D: col=lane&15, row=(lane>>4)*4+reg
//
// R12 (post-mortem R9/R10/R11): VGPR_Count pinned at 64 across THREE
// occupancy hints -> arrays (acc[4][4], vf[4][2], vp[4]) were demoted to
// scratch in the mid-end (rule #20: runtime-indexed ext_vector arrays under
// divergent control flow), never reached the register allocator.  Fix:
// scalarize ALL aggregates to named variables, hand-unroll the PV MFMA
// block, #pragma unroll every vector-element loop.  Keep waves_per_eu(4,4)
// (128-VGPR budget for ~115 live).  Structure identical to R9-R11:
// waves 0-7 (A) produce P(i+1) (QK^T+exp) + stage K; waves 8-15 (B) consume
// P(i) (V loads + P@V, 64-chan slice).  Single raw barrier per window.
// Parities: A writes Pbuf[(i+1)&1], B reads Pbuf[i&1]; A reads Klds[(i+1)&1],
// stages K(i+2)->Klds[i&1] -- disjoint.
//
// ws layout (20.1MB, non-overlapping): fT 64K @0 | gT 64K @64K | Qg 2M @128K |
// Kf 2M @2.125M | Vt 16M @4.125M.
// ---------------------------------------------------------------------------

#define NPOS 4096
#define CCH  512
#define DQK  64
#define LSTR 72   // LDS row stride (elements): 144B rows, 16B-aligned frags

typedef __attribute__((ext_vector_type(8)))  short s8v;   // 8 bf16 (4 VGPR)
typedef __attribute__((ext_vector_type(4)))  short s4v;   // 4 bf16
typedef __attribute__((ext_vector_type(4)))  float f4v;

__device__ __forceinline__ float bf2f(unsigned short u) {
    unsigned int x = ((unsigned int)u) << 16;
    return __builtin_bit_cast(float, x);
}
__device__ __forceinline__ unsigned short f2bf(float f) {
    unsigned int u = __builtin_bit_cast(unsigned int, f);
    u += 0x7fffu + ((u >> 16) & 1u);   // round-to-nearest-even
    return (unsigned short)(u >> 16);
}

// Barrier with LDS visibility but NO vmcnt drain.
__device__ __forceinline__ void sync_lds() {
    asm volatile("s_waitcnt lgkmcnt(0)" ::: "memory");
    __builtin_amdgcn_s_barrier();
}

#define MFMA16(a, bfrag, c) __builtin_amdgcn_mfma_f32_16x16x32_bf16((a), (bfrag), (c), 0, 0, 0)

// --------------------------- weight transpose ------------------------------
__global__ __launch_bounds__(256) void wt_kernel(
    const float* __restrict__ f, const float* __restrict__ g,
    unsigned short* __restrict__ fT, unsigned short* __restrict__ gT)
{
    int gid = blockIdx.x * 256 + threadIdx.x;
    for (int e = 0; e < 4; ++e) {
        int i = e * 16384 + gid;
        int which = i >> 15;
        int j = i & 32767;
        int d = j >> 9, k = j & 511;
        const float* s = which ? g : f;
        unsigned short* dst = which ? gT : fT;
        dst[j] = f2bf(s[k * 64 + d]);
    }
}

// ----------------------------- V transpose ---------------------------------
__global__ __launch_bounds__(256) void vt_kernel(
    const float* __restrict__ ih, unsigned short* __restrict__ Vt)
{
    __shared__ unsigned short T[64 * 65];
    const int tid = threadIdx.x;
    const int bidx = blockIdx.x;
    const int bb = bidx >> 9;
    const int rem = bidx & 511;
    const int ct = rem >> 6;
    const int nt = rem & 63;

    for (int p = 0; p < 4; ++p) {
        int idx = p * 256 + tid;
        int r = idx >> 4, gg = idx & 15;
        f4v v = *(const f4v*)(ih + ((size_t)bb * NPOS + nt * 64 + r) * CCH + ct * 64 + gg * 4);
        #pragma unroll
        for (int j = 0; j < 4; ++j) T[r * 65 + gg * 4 + j] = f2bf(v[j]);
    }
    __syncthreads();
    for (int p = 0; p < 2; ++p) {
        int idx = p * 256 + tid;
        int c = idx >> 3, ng = idx & 7;
        unsigned short tmp[8];
        #pragma unroll
        for (int j = 0; j < 8; ++j) tmp[j] = T[(ng * 8 + j) * 65 + c];
        *(s8v*)(Vt + ((size_t)bb * CCH + ct * 64 + c) * NPOS + nt * 64 + ng * 8) = *(const s8v*)tmp;
    }
}

// ------------------------------ projections --------------------------------
__global__ __launch_bounds__(256) void proj_kernel(
    const float* __restrict__ x,  const float* __restrict__ ih,
    const unsigned short* __restrict__ gT, const unsigned short* __restrict__ fT,
    unsigned short* __restrict__ Qg, unsigned short* __restrict__ Kf)
{
    __shared__ __align__(16) short Alds[128 * LSTR];
    __shared__ __align__(16) short Wlds[64 * LSTR];
    const int tid = threadIdx.x;
    const int wave = tid >> 6, lane = tid & 63;
    const int n15 = lane & 15, quad = lane >> 4;
    const int which = blockIdx.x >> 7;
    const int rb = (blockIdx.x & 127) * 128;
    const float* src = which ? ih : x;
    const unsigned short* wT  = which ? fT : gT;
    unsigned short* dst = which ? Kf : Qg;

    f4v acc[2][4];
    #pragma unroll
    for (int i = 0; i < 2; ++i)
        #pragma unroll
        for (int j = 0; j < 4; ++j)
            acc[i][j] = f4v{0.f, 0.f, 0.f, 0.f};

    f4v areg[8];
    s8v wreg[2];
    #pragma unroll
    for (int p = 0; p < 8; ++p) {
        int idx = p * 256 + tid;
        int r = idx >> 4, gg = idx & 15;
        areg[p] = *(const f4v*)(src + (size_t)(rb + r) * CCH + gg * 4);
    }
    #pragma unroll
    for (int p = 0; p < 2; ++p) {
        int idx = p * 256 + tid;
        int c = idx >> 3, gg = idx & 7;
        wreg[p] = *(const s8v*)(wT + (size_t)c * CCH + gg * 8);
    }

    for (int kc = 0; kc < 8; ++kc) {
        #pragma unroll
        for (int p = 0; p < 8; ++p) {
            int idx = p * 256 + tid;
            int r = idx >> 4, gg = idx & 15;
            s4v tv;
            #pragma unroll
            for (int j = 0; j < 4; ++j) tv[j] = (short)f2bf(areg[p][j]);
            *(s4v*)&Alds[r * LSTR + gg * 4] = tv;
        }
        #pragma unroll
        for (int p = 0; p < 2; ++p) {
            int idx = p * 256 + tid;
            int c = idx >> 3, gg = idx & 7;
            *(s8v*)&Wlds[c * LSTR + gg * 8] = wreg[p];
        }
        if (kc < 7) {
            #pragma unroll
            for (int p = 0; p < 8; ++p) {
                int idx = p * 256 + tid;
                int r = idx >> 4, gg = idx & 15;
                areg[p] = *(const f4v*)(src + (size_t)(rb + r) * CCH + (kc + 1) * 64 + gg * 4);
            }
            #pragma unroll
            for (int p = 0; p < 2; ++p) {
                int idx = p * 256 + tid;
                int c = idx >> 3, gg = idx & 7;
                wreg[p] = *(const s8v*)(wT + (size_t)c * CCH + (kc + 1) * 64 + gg * 8);
            }
        }
        sync_lds();
        #pragma unroll
        for (int kk = 0; kk < 2; ++kk) {
            s8v af0 = *(const s8v*)&Alds[(wave * 32 +      n15) * LSTR + kk * 32 + quad * 8];
            s8v af1 = *(const s8v*)&Alds[(wave * 32 + 16 + n15) * LSTR + kk * 32 + quad * 8];
            #pragma unroll
            for (int ct = 0; ct < 4; ++ct) {
                s8v bf = *(const s8v*)&Wlds[(ct * 16 + n15) * LSTR + kk * 32 + quad * 8];
                acc[0][ct] = MFMA16(af0, bf, acc[0][ct]);
                acc[1][ct] = MFMA16(af1, bf, acc[1][ct]);
            }
        }
        sync_lds();
    }
    #pragma unroll
    for (int rt = 0; rt < 2; ++rt)
        #pragma unroll
        for (int ct = 0; ct < 4; ++ct)
            #pragma unroll
            for (int r = 0; r < 4; ++r) {
                int row = wave * 32 + rt * 16 + quad * 4 + r;
                int col = ct * 16 + n15;
                dst[(size_t)(rb + row) * DQK + col] = f2bf(acc[rt][ct][r]);
            }
}

// ------------------------------ flash attention ----------------------------
// Role-split, fully scalarized (no aggregates that can demote to scratch).
__global__ __launch_bounds__(1024)
__attribute__((amdgpu_waves_per_eu(4, 4)))
void flash_kernel(
    const unsigned short* __restrict__ Qg,
    const unsigned short* __restrict__ Kf,
    const unsigned short* __restrict__ Vt,
    const float* __restrict__ xin,
    const float* __restrict__ gptr,
    float* __restrict__ out)
{
    __shared__ __align__(16) short Klds[2 * 64 * LSTR];
    __shared__ __align__(16) short Plds[2 * 64 * LSTR];
    __shared__ float l_part[2][64];
    __shared__ float l_s[64];

    const int tid = threadIdx.x;
    const int wave = tid >> 6;
    const int lane = tid & 63;
    const int n15 = lane & 15, quad = lane >> 4;
    const int bid = blockIdx.x;
    const int xcd = bid & 7;
    const int b = xcd >> 1;
    const int qt = (xcd & 1) + ((bid >> 3) << 1);
    const int qbase = qt * 64;

    const float SOFT_M = 20.0f;
    const bool isA = (wave < 8);
    const int NT = NPOS / 64;

    // ---- A state (scalar) ----
    const int ti = wave >> 1;
    const int mi0 = (wave & 1) * 2;
    s8v qf0, qf1;
    f4v lsum = f4v{0.f, 0.f, 0.f, 0.f};
    const int kr = tid >> 3, kg = tid & 7;
    const unsigned short* kbase_p = Kf + ((size_t)b * NPOS + kr) * DQK + kg * 8;
    s8v kreg;

    // ---- B state (scalar) ----
    const int cb = (wave - 8) * 64;
    f4v a00, a01, a02, a03, a10, a11, a12, a13;
    f4v a20, a21, a22, a23, a30, a31, a32, a33;
    const unsigned short* vp0;
    const unsigned short* vp1;
    const unsigned short* vp2;
    const unsigned short* vp3;

    if (isA) {
        const unsigned short* qp =
            Qg + ((size_t)b * NPOS + qbase + ti * 16 + n15) * DQK + quad * 8;
        qf0 = *(const s8v*)(qp);
        qf1 = *(const s8v*)(qp + 32);
        kreg = *(const s8v*)(kbase_p);
        *(s8v*)&Klds[kr * LSTR + kg * 8] = kreg;
        kreg = *(const s8v*)(kbase_p + (size_t)64 * DQK);
    } else {
        const f4v z = f4v{0.f, 0.f, 0.f, 0.f};
        a00 = z; a01 = z; a02 = z; a03 = z;
        a10 = z; a11 = z; a12 = z; a13 = z;
        a20 = z; a21 = z; a22 = z; a23 = z;
        a30 = z; a31 = z; a32 = z; a33 = z;
        const unsigned short* Vb = Vt + (size_t)b * CCH * NPOS;
        vp0 = Vb + (size_t)(cb +  0 + n15) * NPOS + quad * 8;
        vp1 = Vb + (size_t)(cb + 16 + n15) * NPOS + quad * 8;
        vp2 = Vb + (size_t)(cb + 32 + n15) * NPOS + quad * 8;
        vp3 = Vb + (size_t)(cb + 48 + n15) * NPOS + quad * 8;
    }
    sync_lds();   // Klds[0] staged

    if (isA) {
        const short* Kb = &Klds[0];
        short* Pb = &Plds[0];
        #pragma unroll
        for (int mm = 0; mm < 2; ++mm) {
            const int mi = mi0 + mm;
            f4v s4 = f4v{0.f, 0.f, 0.f, 0.f};
            s8v kf0 = *(const s8v*)&Kb[(mi * 16 + n15) * LSTR + quad * 8];
            s8v kf1 = *(const s8v*)&Kb[(mi * 16 + n15) * LSTR + 32 + quad * 8];
            s4 = MFMA16(qf0, kf0, s4);
            s4 = MFMA16(qf1, kf1, s4);
            const int col = mi * 16 + n15;
            const int row0 = ti * 16 + quad * 4;
            #pragma unroll
            for (int r = 0; r < 4; ++r) {
                unsigned short pb = f2bf(__expf(fminf(s4[r], 80.0f) - SOFT_M));
                Pb[(row0 + r) * LSTR + col] = (short)pb;
                lsum[r] += bf2f(pb);
            }
        }
        *(s8v*)&Klds[64 * LSTR + kr * LSTR + kg * 8] = kreg;
        kreg = *(const s8v*)(kbase_p + (size_t)128 * DQK);
    }
    sync_lds();   // Pbuf[0] + Klds[1] ready

    for (int i = 0; i < NT; ++i) {
        if (isA) {
            if (i + 1 < NT) {
                const short* Kb = &Klds[((i + 1) & 1) * 64 * LSTR];
                short* Pb = &Plds[((i + 1) & 1) * 64 * LSTR];
                #pragma unroll
                for (int mm = 0; mm < 2; ++mm) {
                    const int mi = mi0 + mm;
                    f4v s4 = f4v{0.f, 0.f, 0.f, 0.f};
                    s8v kf0 = *(const s8v*)&Kb[(mi * 16 + n15) * LSTR + quad * 8];
                    s8v kf1 = *(const s8v*)&Kb[(mi * 16 + n15) * LSTR + 32 + quad * 8];
                    s4 = MFMA16(qf0, kf0, s4);
                    s4 = MFMA16(qf1, kf1, s4);
                    const int col = mi * 16 + n15;
                    const int row0 = ti * 16 + quad * 4;
                    #pragma unroll
                    for (int r = 0; r < 4; ++r) {
                        unsigned short pb = f2bf(__expf(fminf(s4[r], 80.0f) - SOFT_M));
                        Pb[(row0 + r) * LSTR + col] = (short)pb;
                        lsum[r] += bf2f(pb);
                    }
                }
                if (i + 2 < NT)
                    *(s8v*)&Klds[(i & 1) * 64 * LSTR + kr * LSTR + kg * 8] = kreg;
                if (i + 3 < NT)
                    kreg = *(const s8v*)(kbase_p + (size_t)(i + 3) * 64 * DQK);
            }
        } else {
            const int m0 = i * 64;
            s8v vf00 = *(const s8v*)(vp0 + m0);
            s8v vf01 = *(const s8v*)(vp0 + m0 + 32);
            s8v vf10 = *(const s8v*)(vp1 + m0);
            s8v vf11 = *(const s8v*)(vp1 + m0 + 32);
            s8v vf20 = *(const s8v*)(vp2 + m0);
            s8v vf21 = *(const s8v*)(vp2 + m0 + 32);
            s8v vf30 = *(const s8v*)(vp3 + m0);
            s8v vf31 = *(const s8v*)(vp3 + m0 + 32);
            const short* Pb = &Plds[(i & 1) * 64 * LSTR];
            __builtin_amdgcn_s_setprio(1);
            {   // kk = 0
                s8v af;
                af = *(const s8v*)&Pb[( 0 + n15) * LSTR + quad * 8];
                a00 = MFMA16(af, vf00, a00); a01 = MFMA16(af, vf10, a01);
                a02 = MFMA16(af, vf20, a02); a03 = MFMA16(af, vf30, a03);
                af = *(const s8v*)&Pb[(16 + n15) * LSTR + quad * 8];
                a10 = MFMA16(af, vf00, a10); a11 = MFMA16(af, vf10, a11);
                a12 = MFMA16(af, vf20, a12); a13 = MFMA16(af, vf30, a13);
                af = *(const s8v*)&Pb[(32 + n15) * LSTR + quad * 8];
                a20 = MFMA16(af, vf00, a20); a21 = MFMA16(af, vf10, a21);
                a22 = MFMA16(af, vf20, a22); a23 = MFMA16(af, vf30, a23);
                af = *(const s8v*)&Pb[(48 + n15) * LSTR + quad * 8];
                a30 = MFMA16(af, vf00, a30); a31 = MFMA16(af, vf10, a31);
                a32 = MFMA16(af, vf20, a32); a33 = MFMA16(af, vf30, a33);
            }
            {   // kk = 1
                s8v af;
                af = *(const s8v*)&Pb[( 0 + n15) * LSTR + 32 + quad * 8];
                a00 = MFMA16(af, vf01, a00); a01 = MFMA16(af, vf11, a01);
                a02 = MFMA16(af, vf21, a02); a03 = MFMA16(af, vf31, a03);
                af = *(const s8v*)&Pb[(16 + n15) * LSTR + 32 + quad * 8];
                a10 = MFMA16(af, vf01, a10); a11 = MFMA16(af, vf11, a11);
                a12 = MFMA16(af, vf21, a12); a13 = MFMA16(af, vf31, a13);
                af = *(const s8v*)&Pb[(32 + n15) * LSTR + 32 + quad * 8];
                a20 = MFMA16(af, vf01, a20); a21 = MFMA16(af, vf11, a21);
                a22 = MFMA16(af, vf21, a22); a23 = MFMA16(af, vf31, a23);
                af = *(const s8v*)&Pb[(48 + n15) * LSTR + 32 + quad * 8];
                a30 = MFMA16(af, vf01, a30); a31 = MFMA16(af, vf11, a31);
                a32 = MFMA16(af, vf21, a32); a33 = MFMA16(af, vf31, a33);
            }
            __builtin_amdgcn_s_setprio(0);
        }
        sync_lds();
    }

    // ---- denominator ----
    if (isA) {
        #pragma unroll
        for (int d = 1; d < 16; d <<= 1) {
            #pragma unroll
            for (int r = 0; r < 4; ++r)
                lsum[r] += __shfl_xor(lsum[r], d);
        }
        if (n15 == 0) {
            #pragma unroll
            for (int r = 0; r < 4; ++r)
                l_part[wave & 1][ti * 16 + quad * 4 + r] = lsum[r];
        }
    }
    __syncthreads();
    if (tid < 64) l_s[tid] = l_part[0][tid] + l_part[1][tid];
    __syncthreads();

    // ---- epilogue (B-waves) ----
    if (!isA) {
        const float gamma = gptr[0];
        #define STORE_Q4(Q4, A0, A1, A2, A3)                                     \
        {                                                                        \
            _Pragma("unroll")                                                    \
            for (int r = 0; r < 4; ++r) {                                        \
                const int row = (Q4) * 16 + quad * 4 + r;                        \
                const float sc = gamma / l_s[row];                               \
                const size_t base = ((size_t)b * NPOS + qbase + row) * CCH;      \
                const int c0 = cb + n15;                                         \
                out[base + c0     ] = (A0)[r] * sc + xin[base + c0     ];        \
                out[base + c0 + 16] = (A1)[r] * sc + xin[base + c0 + 16];        \
                out[base + c0 + 32] = (A2)[r] * sc + xin[base + c0 + 32];        \
                out[base + c0 + 48] = (A3)[r] * sc + xin[base + c0 + 48];        \
            }                                                                    \
        }
        STORE_Q4(0, a00, a01, a02, a03)
        STORE_Q4(1, a10, a11, a12, a13)
        STORE_Q4(2, a20, a21, a22, a23)
        STORE_Q4(3, a30, a31, a32, a33)
        #undef STORE_Q4
    }
}

// ---------------------------------------------------------------------------
extern "C" void kernel_launch(void* const* d_in, const int* in_sizes, int n_in,
                              void* d_out, int out_size, void* d_ws, size_t ws_size,
                              hipStream_t stream)
{
    const float* x     = (const float*)d_in[0];
    const float* ih    = (const float*)d_in[1];
    const float* f     = (const float*)d_in[2];
    const float* g     = (const float*)d_in[3];
    const float* gamma = (const float*)d_in[4];
    float* out = (float*)d_out;

    char* ws = (char*)d_ws;
    unsigned short* fT = (unsigned short*)(ws + 0);         // 64x512 bf16 (64KB)
    unsigned short* gT = (unsigned short*)(ws + 65536);     // 64x512 bf16 (64KB)
    unsigned short* Qg = (unsigned short*)(ws + 131072);    // 16384x64 bf16 (2MB)
    unsigned short* Kf = (unsigned short*)(ws + 2228224);   // 16384x64 bf16 (2MB)
    unsigned short* Vt = (unsigned short*)(ws + 4325376);   // 4x512x4096 bf16 (16MB)

    wt_kernel<<<64, 256, 0, stream>>>(f, g, fT, gT);
    vt_kernel<<<2048, 256, 0, stream>>>(ih, Vt);
    proj_kernel<<<256, 256, 0, stream>>>(x, ih, gT, fT, Qg, Kf);
    flash_kernel<<<256, 1024, 0, stream>>>(Qg, Kf, Vt, x, gamma, out);
}

// Round 11
// 266.372 us; speedup vs baseline: 1.2852x; 1.2659x over previous
//
#include <hip/hip_runtime.h>
#include <hip/hip_bf16.h>
#include <cstdint>
#include <cstddef>

// ---------------------------------------------------------------------------
// AttentionLayer: out = gamma * softmax((x@g) @ (input_h@f)^T) @ input_h + x
// B=4, W=64 (N=4096), C=C2=512, D=64.  I/O tensors are FLOAT32.
// Q,K,V,weights bf16 for MFMA; softmax + O-accum fp32.
// Fixed-max softmax: p = exp(min(s,80)-20).
// ALL MFMAs 16x16x32_bf16 (HW-verified maps):
//   A: [m=lane&15][k=(lane>>4)*8+j]   B: [n=lane&15][k=(lane>>4)*8+j]
//   C/D: col=lane&15, row=(lane>>4)*4+reg
//
// R15 = fused-lockstep kernel, third submission.  R13/R14 both died with
// "container failed twice" and NO timing block (failure before acquire
// completed) -> broker infra, not kernel.  Kernel re-audited 3x: uniform
// barriers, disjoint parities, bounded addresses.  Theory unchanged:
// R4/R7/R8 lockstep windows are phase-chunked (all waves on one pipe at a
// time) -> LDS 3.0K + MFMA 1.2K + VALU 1.1K serialize to ~5.3K cyc/window.
// Role-split register-infeasible (R9-R12).  Fix: fuse B(i) + A(i+1) into ONE
// barrier segment, symmetric waves:  [vf(i) | af(i) | kf(i+1) | stage K(i+2)
// | QK(i+1) | PV(i) | exp+Pwrite(i+1)] -> sync.  ~105 live VGPR.
// Parities: B(i) reads P[i&1], A(i+1) writes P[(i+1)&1]; A(i+1) reads
// Klds[(i+1)&1], stage writes K(i+2)->Klds[i&1].  All disjoint.
//
// ws layout (20.1MB, non-overlapping): fT 64K @0 | gT 64K @64K | Qg 2M @128K |
// Kf 2M @2.125M | Vt 16M @4.125M.
// ---------------------------------------------------------------------------

#define NPOS 4096
#define CCH  512
#define DQK  64
#define LSTR 72   // LDS row stride (elements): 144B rows, 16B-aligned frags

typedef __attribute__((ext_vector_type(8)))  short s8v;   // 8 bf16 (4 VGPR)
typedef __attribute__((ext_vector_type(4)))  short s4v;   // 4 bf16
typedef __attribute__((ext_vector_type(4)))  float f4v;

__device__ __forceinline__ float bf2f(unsigned short u) {
    unsigned int x = ((unsigned int)u) << 16;
    return __builtin_bit_cast(float, x);
}
__device__ __forceinline__ unsigned short f2bf(float f) {
    unsigned int u = __builtin_bit_cast(unsigned int, f);
    u += 0x7fffu + ((u >> 16) & 1u);   // round-to-nearest-even
    return (unsigned short)(u >> 16);
}

// Barrier with LDS visibility but NO vmcnt drain.
__device__ __forceinline__ void sync_lds() {
    asm volatile("s_waitcnt lgkmcnt(0)" ::: "memory");
    __builtin_amdgcn_s_barrier();
}

#define MFMA16(a, bfrag, c) __builtin_amdgcn_mfma_f32_16x16x32_bf16((a), (bfrag), (c), 0, 0, 0)

// --------------------------- weight transpose ------------------------------
__global__ __launch_bounds__(256) void wt_kernel(
    const float* __restrict__ f, const float* __restrict__ g,
    unsigned short* __restrict__ fT, unsigned short* __restrict__ gT)
{
    int gid = blockIdx.x * 256 + threadIdx.x;
    for (int e = 0; e < 4; ++e) {
        int i = e * 16384 + gid;
        int which = i >> 15;
        int j = i & 32767;
        int d = j >> 9, k = j & 511;
        const float* s = which ? g : f;
        unsigned short* dst = which ? gT : fT;
        dst[j] = f2bf(s[k * 64 + d]);
    }
}

// ----------------------------- V transpose ---------------------------------
__global__ __launch_bounds__(256) void vt_kernel(
    const float* __restrict__ ih, unsigned short* __restrict__ Vt)
{
    __shared__ unsigned short T[64 * 65];
    const int tid = threadIdx.x;
    const int bidx = blockIdx.x;
    const int bb = bidx >> 9;
    const int rem = bidx & 511;
    const int ct = rem >> 6;
    const int nt = rem & 63;

    for (int p = 0; p < 4; ++p) {
        int idx = p * 256 + tid;
        int r = idx >> 4, gg = idx & 15;
        f4v v = *(const f4v*)(ih + ((size_t)bb * NPOS + nt * 64 + r) * CCH + ct * 64 + gg * 4);
        #pragma unroll
        for (int j = 0; j < 4; ++j) T[r * 65 + gg * 4 + j] = f2bf(v[j]);
    }
    __syncthreads();
    for (int p = 0; p < 2; ++p) {
        int idx = p * 256 + tid;
        int c = idx >> 3, ng = idx & 7;
        unsigned short tmp[8];
        #pragma unroll
        for (int j = 0; j < 8; ++j) tmp[j] = T[(ng * 8 + j) * 65 + c];
        *(s8v*)(Vt + ((size_t)bb * CCH + ct * 64 + c) * NPOS + nt * 64 + ng * 8) = *(const s8v*)tmp;
    }
}

// ------------------------------ projections --------------------------------
__global__ __launch_bounds__(256) void proj_kernel(
    const float* __restrict__ x,  const float* __restrict__ ih,
    const unsigned short* __restrict__ gT, const unsigned short* __restrict__ fT,
    unsigned short* __restrict__ Qg, unsigned short* __restrict__ Kf)
{
    __shared__ __align__(16) short Alds[128 * LSTR];
    __shared__ __align__(16) short Wlds[64 * LSTR];
    const int tid = threadIdx.x;
    const int wave = tid >> 6, lane = tid & 63;
    const int n15 = lane & 15, quad = lane >> 4;
    const int which = blockIdx.x >> 7;
    const int rb = (blockIdx.x & 127) * 128;
    const float* src = which ? ih : x;
    const unsigned short* wT  = which ? fT : gT;
    unsigned short* dst = which ? Kf : Qg;

    f4v acc[2][4];
    #pragma unroll
    for (int i = 0; i < 2; ++i)
        #pragma unroll
        for (int j = 0; j < 4; ++j)
            acc[i][j] = f4v{0.f, 0.f, 0.f, 0.f};

    f4v areg[8];
    s8v wreg[2];
    #pragma unroll
    for (int p = 0; p < 8; ++p) {
        int idx = p * 256 + tid;
        int r = idx >> 4, gg = idx & 15;
        areg[p] = *(const f4v*)(src + (size_t)(rb + r) * CCH + gg * 4);
    }
    #pragma unroll
    for (int p = 0; p < 2; ++p) {
        int idx = p * 256 + tid;
        int c = idx >> 3, gg = idx & 7;
        wreg[p] = *(const s8v*)(wT + (size_t)c * CCH + gg * 8);
    }

    for (int kc = 0; kc < 8; ++kc) {
        #pragma unroll
        for (int p = 0; p < 8; ++p) {
            int idx = p * 256 + tid;
            int r = idx >> 4, gg = idx & 15;
            s4v tv;
            #pragma unroll
            for (int j = 0; j < 4; ++j) tv[j] = (short)f2bf(areg[p][j]);
            *(s4v*)&Alds[r * LSTR + gg * 4] = tv;
        }
        #pragma unroll
        for (int p = 0; p < 2; ++p) {
            int idx = p * 256 + tid;
            int c = idx >> 3, gg = idx & 7;
            *(s8v*)&Wlds[c * LSTR + gg * 8] = wreg[p];
        }
        if (kc < 7) {
            #pragma unroll
            for (int p = 0; p < 8; ++p) {
                int idx = p * 256 + tid;
                int r = idx >> 4, gg = idx & 15;
                areg[p] = *(const f4v*)(src + (size_t)(rb + r) * CCH + (kc + 1) * 64 + gg * 4);
            }
            #pragma unroll
            for (int p = 0; p < 2; ++p) {
                int idx = p * 256 + tid;
                int c = idx >> 3, gg = idx & 7;
                wreg[p] = *(const s8v*)(wT + (size_t)c * CCH + (kc + 1) * 64 + gg * 8);
            }
        }
        sync_lds();
        #pragma unroll
        for (int kk = 0; kk < 2; ++kk) {
            s8v af0 = *(const s8v*)&Alds[(wave * 32 +      n15) * LSTR + kk * 32 + quad * 8];
            s8v af1 = *(const s8v*)&Alds[(wave * 32 + 16 + n15) * LSTR + kk * 32 + quad * 8];
            #pragma unroll
            for (int ct = 0; ct < 4; ++ct) {
                s8v bf = *(const s8v*)&Wlds[(ct * 16 + n15) * LSTR + kk * 32 + quad * 8];
                acc[0][ct] = MFMA16(af0, bf, acc[0][ct]);
                acc[1][ct] = MFMA16(af1, bf, acc[1][ct]);
            }
        }
        sync_lds();
    }
    #pragma unroll
    for (int rt = 0; rt < 2; ++rt)
        #pragma unroll
        for (int ct = 0; ct < 4; ++ct)
            #pragma unroll
            for (int r = 0; r < 4; ++r) {
                int row = wave * 32 + rt * 16 + quad * 4 + r;
                int col = ct * 16 + n15;
                dst[(size_t)(rb + row) * DQK + col] = f2bf(acc[rt][ct][r]);
            }
}

// ------------------------------ flash attention ----------------------------
// Fused lockstep: one block per (batch, 64-row query tile), 16 waves, all
// symmetric.  Wave w: S-tile (ti=w>>2, mi=w&3) for window i+1, PV for its
// 32-chan slice (cb=w*32) for window i -- both in ONE barrier segment.
__global__ __launch_bounds__(1024)
__attribute__((amdgpu_waves_per_eu(4, 4)))
void flash_kernel(
    const unsigned short* __restrict__ Qg,
    const unsigned short* __restrict__ Kf,
    const unsigned short* __restrict__ Vt,
    const float* __restrict__ xin,
    const float* __restrict__ gptr,
    float* __restrict__ out)
{
    __shared__ __align__(16) short Klds[2 * 64 * LSTR];
    __shared__ __align__(16) short Plds[2 * 64 * LSTR];
    __shared__ float l_part[4][64];
    __shared__ float l_s[64];

    const int tid = threadIdx.x;
    const int wave = tid >> 6;
    const int lane = tid & 63;
    const int n15 = lane & 15, quad = lane >> 4;
    const int bid = blockIdx.x;
    const int xcd = bid & 7;
    const int b = xcd >> 1;
    const int qt = (xcd & 1) + ((bid >> 3) << 1);
    const int qbase = qt * 64;

    const float SOFT_M = 20.0f;
    const int NT = NPOS / 64;
    const f4v zero4 = f4v{0.f, 0.f, 0.f, 0.f};

    const int ti = wave >> 2;
    const int mi = wave & 3;
    const int cb = wave * 32;

    f4v acc[4][2];
    #pragma unroll
    for (int i = 0; i < 4; ++i) {
        acc[i][0] = zero4;
        acc[i][1] = zero4;
    }
    f4v lsum = zero4;

    s8v qf0, qf1;
    {
        const unsigned short* qp =
            Qg + ((size_t)b * NPOS + qbase + ti * 16 + n15) * DQK + quad * 8;
        qf0 = *(const s8v*)(qp);
        qf1 = *(const s8v*)(qp + 32);
    }
    const unsigned short* vp0 =
        Vt + ((size_t)b * CCH + cb + n15) * NPOS + quad * 8;
    const unsigned short* vp1 = vp0 + (size_t)16 * NPOS;

    const int kr = tid >> 3, kg = tid & 7;   // staging coords (tid<512)
    const unsigned short* kbase_p = Kf + ((size_t)b * NPOS + kr) * DQK + kg * 8;
    s8v kreg;

    // ---- prologue: stage K(0); A(0) -> P[0]; stage K(1) ----
    if (tid < 512) {
        kreg = *(const s8v*)(kbase_p);
        *(s8v*)&Klds[kr * LSTR + kg * 8] = kreg;
        kreg = *(const s8v*)(kbase_p + (size_t)64 * DQK);
    }
    sync_lds();   // Klds[0] visible
    {
        const short* Kb = &Klds[0];
        short* Pb = &Plds[0];
        s8v kf0 = *(const s8v*)&Kb[(mi * 16 + n15) * LSTR + quad * 8];
        s8v kf1 = *(const s8v*)&Kb[(mi * 16 + n15) * LSTR + 32 + quad * 8];
        f4v s4 = zero4;
        s4 = MFMA16(qf0, kf0, s4);
        s4 = MFMA16(qf1, kf1, s4);
        const int col = mi * 16 + n15;
        const int row0 = ti * 16 + quad * 4;
        #pragma unroll
        for (int r = 0; r < 4; ++r) {
            unsigned short pb = f2bf(__expf(fminf(s4[r], 80.0f) - SOFT_M));
            Pb[(row0 + r) * LSTR + col] = (short)pb;
            lsum[r] += bf2f(pb);
        }
    }
    if (tid < 512) {
        *(s8v*)&Klds[64 * LSTR + kr * LSTR + kg * 8] = kreg;   // stage K(1)
        kreg = *(const s8v*)(kbase_p + (size_t)128 * DQK);      // K(2)
    }
    sync_lds();   // P[0] + Klds[1] visible

    // ---- main loop: segment i = { vf(i), B(i) <interleaved> A(i+1),
    //      stage K(i+2) } -> sync.  Mixed stream feeds all pipes. ----
    for (int i = 0; i < NT; ++i) {
        const int m0 = i * 64;
        // V fragments for PV(i) (global, L2-hot; consumed mid-segment)
        s8v vf00 = *(const s8v*)(vp0 + m0);
        s8v vf01 = *(const s8v*)(vp0 + m0 + 32);
        s8v vf10 = *(const s8v*)(vp1 + m0);
        s8v vf11 = *(const s8v*)(vp1 + m0 + 32);

        const short* Pb = &Plds[(i & 1) * 64 * LSTR];
        // P fragments kk=0
        s8v af0_0 = *(const s8v*)&Pb[( 0 + n15) * LSTR + quad * 8];
        s8v af1_0 = *(const s8v*)&Pb[(16 + n15) * LSTR + quad * 8];
        s8v af2_0 = *(const s8v*)&Pb[(32 + n15) * LSTR + quad * 8];
        s8v af3_0 = *(const s8v*)&Pb[(48 + n15) * LSTR + quad * 8];

        // K fragments for A(i+1)
        s8v kf0, kf1;
        const bool doA = (i + 1 < NT);
        if (doA) {
            const short* Kb = &Klds[((i + 1) & 1) * 64 * LSTR];
            kf0 = *(const s8v*)&Kb[(mi * 16 + n15) * LSTR + quad * 8];
            kf1 = *(const s8v*)&Kb[(mi * 16 + n15) * LSTR + 32 + quad * 8];
        }
        // stage K(i+2) -> Klds[i&1]; prefetch K(i+3)
        if (tid < 512 && i + 2 < NT) {
            *(s8v*)&Klds[(i & 1) * 64 * LSTR + kr * LSTR + kg * 8] = kreg;
            if (i + 3 < NT)
                kreg = *(const s8v*)(kbase_p + (size_t)(i + 3) * 64 * DQK);
        }

        // QK^T MFMAs for A(i+1) (result consumed at segment end by exp)
        f4v s4 = zero4;
        if (doA) {
            s4 = MFMA16(qf0, kf0, s4);
            s4 = MFMA16(qf1, kf1, s4);
        }

        // PV kk=0
        acc[0][0] = MFMA16(af0_0, vf00, acc[0][0]);
        acc[0][1] = MFMA16(af0_0, vf10, acc[0][1]);
        acc[1][0] = MFMA16(af1_0, vf00, acc[1][0]);
        acc[1][1] = MFMA16(af1_0, vf10, acc[1][1]);
        acc[2][0] = MFMA16(af2_0, vf00, acc[2][0]);
        acc[2][1] = MFMA16(af2_0, vf10, acc[2][1]);
        acc[3][0] = MFMA16(af3_0, vf00, acc[3][0]);
        acc[3][1] = MFMA16(af3_0, vf10, acc[3][1]);

        // P fragments kk=1
        s8v af0_1 = *(const s8v*)&Pb[( 0 + n15) * LSTR + 32 + quad * 8];
        s8v af1_1 = *(const s8v*)&Pb[(16 + n15) * LSTR + 32 + quad * 8];
        s8v af2_1 = *(const s8v*)&Pb[(32 + n15) * LSTR + 32 + quad * 8];
        s8v af3_1 = *(const s8v*)&Pb[(48 + n15) * LSTR + 32 + quad * 8];

        // PV kk=1
        acc[0][0] = MFMA16(af0_1, vf01, acc[0][0]);
        acc[0][1] = MFMA16(af0_1, vf11, acc[0][1]);
        acc[1][0] = MFMA16(af1_1, vf01, acc[1][0]);
        acc[1][1] = MFMA16(af1_1, vf11, acc[1][1]);
        acc[2][0] = MFMA16(af2_1, vf01, acc[2][0]);
        acc[2][1] = MFMA16(af2_1, vf11, acc[2][1]);
        acc[3][0] = MFMA16(af3_1, vf01, acc[3][0]);
        acc[3][1] = MFMA16(af3_1, vf11, acc[3][1]);

        // exp + P-write for A(i+1) (VALU tail; s4 long ready)
        if (doA) {
            short* Pw = &Plds[((i + 1) & 1) * 64 * LSTR];
            const int col = mi * 16 + n15;
            const int row0 = ti * 16 + quad * 4;
            #pragma unroll
            for (int r = 0; r < 4; ++r) {
                unsigned short pb = f2bf(__expf(fminf(s4[r], 80.0f) - SOFT_M));
                Pw[(row0 + r) * LSTR + col] = (short)pb;
                lsum[r] += bf2f(pb);
            }
        }
        sync_lds();
        // parities: B(i) read P[i&1]; A(i+1) wrote P[(i+1)&1]; A(i+1) read
        // Klds[(i+1)&1]; stage wrote K(i+2)->Klds[i&1].  All disjoint; the
        // last reader/writer of each buffer is one full sync behind.
    }

    // ---- denominator: reduce lsum over n15 lanes, combine 4 mi waves ----
    #pragma unroll
    for (int d = 1; d < 16; d <<= 1) {
        #pragma unroll
        for (int r = 0; r < 4; ++r)
            lsum[r] += __shfl_xor(lsum[r], d);
    }
    if (n15 == 0) {
        #pragma unroll
        for (int r = 0; r < 4; ++r)
            l_part[mi][ti * 16 + quad * 4 + r] = lsum[r];
    }
    __syncthreads();
    if (tid < 64)
        l_s[tid] = l_part[0][tid] + l_part[1][tid] + l_part[2][tid] + l_part[3][tid];
    __syncthreads();

    // ---- epilogue: out = gamma * O / l + x ----
    const float gamma = gptr[0];
    #pragma unroll
    for (int q4 = 0; q4 < 4; ++q4) {
        #pragma unroll
        for (int r = 0; r < 4; ++r) {
            const int row = q4 * 16 + quad * 4 + r;
            const float sc = gamma / l_s[row];
            const size_t base = ((size_t)b * NPOS + qbase + row) * CCH;
            const int col0 = cb + n15;
            const int col1 = cb + 16 + n15;
            out[base + col0] = acc[q4][0][r] * sc + xin[base + col0];
            out[base + col1] = acc[q4][1][r] * sc + xin[base + col1];
        }
    }
}

// ---------------------------------------------------------------------------
extern "C" void kernel_launch(void* const* d_in, const int* in_sizes, int n_in,
                              void* d_out, int out_size, void* d_ws, size_t ws_size,
                              hipStream_t stream)
{
    const float* x     = (const float*)d_in[0];
    const float* ih    = (const float*)d_in[1];
    const float* f     = (const float*)d_in[2];
    const float* g     = (const float*)d_in[3];
    const float* gamma = (const float*)d_in[4];
    float* out = (float*)d_out;

    char* ws = (char*)d_ws;
    unsigned short* fT = (unsigned short*)(ws + 0);         // 64x512 bf16 (64KB)
    unsigned short* gT = (unsigned short*)(ws + 65536);     // 64x512 bf16 (64KB)
    unsigned short* Qg = (unsigned short*)(ws + 131072);    // 16384x64 bf16 (2MB)
    unsigned short* Kf = (unsigned short*)(ws + 2228224);   // 16384x64 bf16 (2MB)
    unsigned short* Vt = (unsigned short*)(ws + 4325376);   // 4x512x4096 bf16 (16MB)

    wt_kernel<<<64, 256, 0, stream>>>(f, g, fT, gT);
    vt_kernel<<<2048, 256, 0, stream>>>(ih, Vt);
    proj_kernel<<<256, 256, 0, stream>>>(x, ih, gT, fT, Qg, Kf);
    flash_kernel<<<256, 1024, 0, stream>>>(Qg, Kf, Vt, x, gamma, out);
}